// Round 1
// 593.502 us; speedup vs baseline: 1.1798x; 1.1798x over previous
//
#include <hip/hip_runtime.h>
#include <cstdint>
#include <cstddef>

#define NB 4
#define HH 96
#define WW 96
#define CHN 256
#define CC 64
#define LL 9216
#define NHASH 4
#define HBK 64
#define CHK 144
#define NCHUNK 64
#define NJ 36864   // NHASH * LL

typedef __attribute__((ext_vector_type(8))) short bf16x8;
typedef __attribute__((ext_vector_type(8))) unsigned short u16x8;
typedef __attribute__((ext_vector_type(4))) float f32x4;

__device__ __forceinline__ unsigned short f2b(float f) {
    unsigned int x = __float_as_uint(f);
    x += 0x7FFFu + ((x >> 16) & 1u);
    return (unsigned short)(x >> 16);
}
__device__ __forceinline__ float b2f(unsigned short u) {
    return __uint_as_float(((unsigned int)u) << 16);
}

// ---------------------------------------------------------------- conv 3x3 SAME (fp32 — match path, feeds hashing)
__global__ __launch_bounds__(256) void conv3x3_k(
    const float* __restrict__ in, const float* __restrict__ wgt,
    const float* __restrict__ bias, float* __restrict__ out, int CO)
{
    __shared__ float inb[64][36];
    __shared__ float wb[32][68];
    const int n = blockIdx.z;
    const int p0 = blockIdx.x * 64;
    const int co0 = blockIdx.y * 64;
    const int tid = threadIdx.x;
    const int cg = tid & 15;
    const int pg = tid >> 4;
    float acc[4][4];
#pragma unroll
    for (int a = 0; a < 4; a++)
#pragma unroll
        for (int b = 0; b < 4; b++) acc[a][b] = 0.f;
    const float* inN = in + (size_t)n * LL * CHN;
    for (int ky = 0; ky < 3; ky++)
    for (int kx = 0; kx < 3; kx++) {
        for (int ci0 = 0; ci0 < CHN; ci0 += 32) {
#pragma unroll
            for (int ld = 0; ld < 2; ld++) {
                int lin = tid * 2 + ld;
                int px = lin >> 3;
                int c4 = (lin & 7) * 4;
                int p = p0 + px;
                int hh = p / WW + ky - 1;
                int ww2 = p % WW + kx - 1;
                float4 v = make_float4(0.f, 0.f, 0.f, 0.f);
                if (hh >= 0 && hh < HH && ww2 >= 0 && ww2 < WW)
                    v = *(const float4*)(inN + (size_t)(hh * WW + ww2) * CHN + ci0 + c4);
                *(float4*)&inb[px][c4] = v;
            }
#pragma unroll
            for (int ld = 0; ld < 2; ld++) {
                int lin = tid * 2 + ld;
                int ci = lin >> 4;
                int c4 = (lin & 15) * 4;
                float4 v = *(const float4*)(wgt + (size_t)((ky * 3 + kx) * CHN + ci0 + ci) * CO + co0 + c4);
                *(float4*)&wb[ci][c4] = v;
            }
            __syncthreads();
#pragma unroll
            for (int s = 0; s < 8; s++) {
                int ci = s * 4;
                float4 bv0 = *(float4*)&wb[ci + 0][cg * 4];
                float4 bv1 = *(float4*)&wb[ci + 1][cg * 4];
                float4 bv2 = *(float4*)&wb[ci + 2][cg * 4];
                float4 bv3 = *(float4*)&wb[ci + 3][cg * 4];
#pragma unroll
                for (int k = 0; k < 4; k++) {
                    float4 av = *(float4*)&inb[pg * 4 + k][ci];
                    acc[k][0] = fmaf(av.x, bv0.x, fmaf(av.y, bv1.x, fmaf(av.z, bv2.x, fmaf(av.w, bv3.x, acc[k][0]))));
                    acc[k][1] = fmaf(av.x, bv0.y, fmaf(av.y, bv1.y, fmaf(av.z, bv2.y, fmaf(av.w, bv3.y, acc[k][1]))));
                    acc[k][2] = fmaf(av.x, bv0.z, fmaf(av.y, bv1.z, fmaf(av.z, bv2.z, fmaf(av.w, bv3.z, acc[k][2]))));
                    acc[k][3] = fmaf(av.x, bv0.w, fmaf(av.y, bv1.w, fmaf(av.z, bv2.w, fmaf(av.w, bv3.w, acc[k][3]))));
                }
            }
            __syncthreads();
        }
    }
    float* outN = out + (size_t)n * LL * CO;
#pragma unroll
    for (int k = 0; k < 4; k++) {
        int p = p0 + pg * 4 + k;
        float4 o;
        o.x = acc[k][0] + bias[co0 + cg * 4 + 0];
        o.y = acc[k][1] + bias[co0 + cg * 4 + 1];
        o.z = acc[k][2] + bias[co0 + cg * 4 + 2];
        o.w = acc[k][3] + bias[co0 + cg * 4 + 3];
        *(float4*)(outN + (size_t)p * CO + co0 + cg * 4) = o;
    }
}

// ---------------------------------------------------------------- fp32 transpose (match embedding) + bf16 copy
__global__ __launch_bounds__(256) void transpose_k(const float* __restrict__ in, float* __restrict__ out,
                                                   unsigned short* __restrict__ out_bf, int R, int Cc)
{
    __shared__ float tl[32][33];
    const int n = blockIdx.z;
    const size_t base = (size_t)n * R * Cc;
    int c0 = blockIdx.x * 32, r0 = blockIdx.y * 32;
    int tx = threadIdx.x & 31, ty0 = threadIdx.x >> 5;
#pragma unroll
    for (int i = 0; i < 32; i += 8)
        tl[ty0 + i][tx] = in[base + (size_t)(r0 + ty0 + i) * Cc + c0 + tx];
    __syncthreads();
#pragma unroll
    for (int i = 0; i < 32; i += 8) {
        float v = tl[tx][ty0 + i];
        size_t o = base + (size_t)(c0 + ty0 + i) * R + r0 + tx;
        out[o] = v;
        out_bf[o] = f2b(v);
    }
}

// ---------------------------------------------------------------- input fp32 -> bf16
__global__ __launch_bounds__(256) void cvt_in_k(const float* __restrict__ in, unsigned short* __restrict__ out)
{
    size_t g = ((size_t)blockIdx.x * 256 + threadIdx.x) * 8;
    float4 v0 = *(const float4*)(in + g);
    float4 v1 = *(const float4*)(in + g + 4);
    u16x8 o;
    o[0] = f2b(v0.x); o[1] = f2b(v0.y); o[2] = f2b(v0.z); o[3] = f2b(v0.w);
    o[4] = f2b(v1.x); o[5] = f2b(v1.y); o[6] = f2b(v1.z); o[7] = f2b(v1.w);
    *(u16x8*)(out + g) = o;
}

// ---------------------------------------------------------------- w_asm [tap][ci][co] fp32 -> wT [tap][co][ci] bf16
__global__ __launch_bounds__(256) void cvt_wT_k(const float* __restrict__ w, unsigned short* __restrict__ wT)
{
    __shared__ float tl[32][33];
    const int tap = blockIdx.z;
    const int c0 = blockIdx.x * 32;
    const int o0 = blockIdx.y * 32;
    const int tx = threadIdx.x & 31, ty0 = threadIdx.x >> 5;
#pragma unroll
    for (int i = 0; i < 32; i += 8)
        tl[ty0 + i][tx] = w[((size_t)tap * 256 + c0 + ty0 + i) * 256 + o0 + tx];
    __syncthreads();
#pragma unroll
    for (int i = 0; i < 32; i += 8)
        wT[((size_t)tap * 256 + o0 + ty0 + i) * 256 + c0 + tx] = f2b(tl[tx][ty0 + i]);
}

// ---------------------------------------------------------------- MFMA conv 3x3 (value path, bf16)
__global__ __launch_bounds__(256) void conv_mfma_k(
    const unsigned short* __restrict__ in_bf, const unsigned short* __restrict__ wT,
    const float* __restrict__ bias, unsigned short* __restrict__ ya_bf)
{
    __shared__ short As[128 * 32];
    __shared__ short Bs[128 * 32];
    const int n = blockIdx.z, p0 = blockIdx.x * 128, co0 = blockIdx.y * 128;
    const int tid = threadIdx.x;
    const int w = tid >> 6, wr = w >> 1, wc = w & 1;
    const int lane = tid & 63, lm = lane & 15, lq = lane >> 4;
    const int r = tid >> 1, hf = tid & 1;
    const int p = p0 + r, py = p / WW, px = p % WW;
    const unsigned short* inN = in_bf + (size_t)n * LL * CHN;

    f32x4 acc[4][4];
#pragma unroll
    for (int a = 0; a < 4; a++)
#pragma unroll
        for (int b = 0; b < 4; b++) acc[a][b] = (f32x4){0.f, 0.f, 0.f, 0.f};

    for (int tap = 0; tap < 9; tap++) {
        const int ky = tap / 3, kx = tap - ky * 3;
        const int sy = py + ky - 1, sx = px + kx - 1;
        const bool valid = ((unsigned)sy < HH) && ((unsigned)sx < WW);
        const unsigned short* asrc = inN + (size_t)(sy * WW + sx) * CHN + hf * 16;
        const unsigned short* bsrc = wT + ((size_t)tap * 256 + co0 + r) * 256 + hf * 16;
        for (int ci0 = 0; ci0 < 256; ci0 += 32) {
            u16x8 av0 = (u16x8){0,0,0,0,0,0,0,0}, av1 = (u16x8){0,0,0,0,0,0,0,0};
            if (valid) {
                av0 = *(const u16x8*)(asrc + ci0);
                av1 = *(const u16x8*)(asrc + ci0 + 8);
            }
            u16x8 bv0 = *(const u16x8*)(bsrc + ci0);
            u16x8 bv1 = *(const u16x8*)(bsrc + ci0 + 8);
            __syncthreads();
            *(u16x8*)&As[r * 32 + hf * 16]     = av0;
            *(u16x8*)&As[r * 32 + hf * 16 + 8] = av1;
            *(u16x8*)&Bs[r * 32 + hf * 16]     = bv0;
            *(u16x8*)&Bs[r * 32 + hf * 16 + 8] = bv1;
            __syncthreads();
            bf16x8 af[4], bf[4];
#pragma unroll
            for (int mt = 0; mt < 4; mt++)
                af[mt] = *(const bf16x8*)&As[(wr * 64 + mt * 16 + lm) * 32 + lq * 8];
#pragma unroll
            for (int nt = 0; nt < 4; nt++)
                bf[nt] = *(const bf16x8*)&Bs[(wc * 64 + nt * 16 + lm) * 32 + lq * 8];
#pragma unroll
            for (int mt = 0; mt < 4; mt++)
#pragma unroll
                for (int nt = 0; nt < 4; nt++)
                    acc[mt][nt] = __builtin_amdgcn_mfma_f32_16x16x32_bf16(af[mt], bf[nt], acc[mt][nt], 0, 0, 0);
        }
    }
    float bv[4];
#pragma unroll
    for (int nt = 0; nt < 4; nt++) bv[nt] = bias[co0 + wc * 64 + nt * 16 + lm];
#pragma unroll
    for (int mt = 0; mt < 4; mt++) {
#pragma unroll
        for (int r4 = 0; r4 < 4; r4++) {
            int row = p0 + wr * 64 + mt * 16 + lq * 4 + r4;
            unsigned short* od = ya_bf + ((size_t)n * LL + row) * CHN + co0 + wc * 64;
#pragma unroll
            for (int nt = 0; nt < 4; nt++)
                od[nt * 16 + lm] = f2b(acc[mt][nt][r4] + bv[nt]);
        }
    }
}

// ---------------------------------------------------------------- bf16 transpose: ya_bf (viewed [256][9216]) -> yaT [9216][256]
__global__ __launch_bounds__(256) void transpose_bf_k(const unsigned short* __restrict__ in,
                                                      unsigned short* __restrict__ out)
{
    __shared__ unsigned short tl[64][65];
    const int n = blockIdx.z;
    const size_t base = (size_t)n * LL * CHN;
    const int t0 = blockIdx.x * 64, e0 = blockIdx.y * 64;
    const int tx = threadIdx.x & 63, ty0 = threadIdx.x >> 6;
#pragma unroll
    for (int i = 0; i < 16; i++) {
        int row = ty0 + i * 4;
        tl[row][tx] = in[base + (size_t)(e0 + row) * LL + t0 + tx];
    }
    __syncthreads();
#pragma unroll
    for (int i = 0; i < 16; i++) {
        int row = ty0 + i * 4;
        out[base + (size_t)(t0 + row) * CHN + e0 + tx] = tl[tx][row];
    }
}

// ---------------------------------------------------------------- hashing: codes + squared norms (fp32!)
__global__ __launch_bounds__(256) void hash_k(const float* __restrict__ xmT, const float* __restrict__ rot,
                                              int* __restrict__ codes, float* __restrict__ ssq)
{
    __shared__ float rs[128 * 68];   // [hi][f], stride 68
    for (int e = threadIdx.x; e < 8192; e += 256) {
        int hi = e >> 6, f = e & 63;
        rs[hi * 68 + f] = rot[f * 128 + hi];
    }
    __syncthreads();
    int g = blockIdx.x * 256 + threadIdx.x;
    int n = g / LL, t = g % LL;
    float4 x4[16];
    const float* src = xmT + (size_t)g * CC;
#pragma unroll
    for (int f4 = 0; f4 < 16; f4++) x4[f4] = *(const float4*)(src + f4 * 4);
    float ss = 0.f;
#pragma unroll
    for (int f4 = 0; f4 < 16; f4++)
        ss += x4[f4].x * x4[f4].x + x4[f4].y * x4[f4].y + x4[f4].z * x4[f4].z + x4[f4].w * x4[f4].w;
    ssq[g] = ss;
    for (int h = 0; h < NHASH; h++) {
        float bp = -1e30f, bn = -1e30f;
        int ip = 0, inn = 0;
        for (int i = 0; i < 32; i++) {
            const float* rr = &rs[(h * 32 + i) * 68];
            float d0 = 0.f, d1 = 0.f, d2 = 0.f, d3 = 0.f;
#pragma unroll
            for (int f4 = 0; f4 < 16; f4++) {
                float4 r4 = *(const float4*)(rr + f4 * 4);
                d0 = fmaf(x4[f4].x, r4.x, d0);
                d1 = fmaf(x4[f4].y, r4.y, d1);
                d2 = fmaf(x4[f4].z, r4.z, d2);
                d3 = fmaf(x4[f4].w, r4.w, d3);
            }
            float d = (d0 + d1) + (d2 + d3);
            if (d > bp) { bp = d; ip = i; }
            if (-d > bn) { bn = -d; inn = i; }
        }
        int code = (bp >= bn) ? ip : (32 + inn);
        codes[(size_t)n * NJ + h * LL + t] = code + h * HBK;
    }
}

// ---------------------------------------------------------------- stable counting sort (256 buckets)
__global__ __launch_bounds__(256) void sort_hist_k(const int* __restrict__ codes, int* __restrict__ hist,
                                                   int* __restrict__ rank)
{
    __shared__ int lc[256];
    __shared__ int lh[256];
    const int n = blockIdx.y, seg = blockIdx.x, tid = threadIdx.x;
    int j = seg * 256 + tid;
    int c = codes[(size_t)n * NJ + j];
    lc[tid] = c;
    lh[tid] = 0;
    __syncthreads();
    int r = 0;
    for (int q = 0; q < tid; q++) r += (lc[q] == c) ? 1 : 0;
    atomicAdd(&lh[c], 1);
    __syncthreads();
    rank[(size_t)n * NJ + j] = r;
    hist[(size_t)n * NJ + tid * 144 + seg] = lh[tid];
}

__global__ __launch_bounds__(256) void sort_scan_k(int* __restrict__ hist)
{
    const int n = blockIdx.x;
    const int key = threadIdx.x;
    int* hn = hist + (size_t)n * NJ;
    int sum = 0;
    for (int s = 0; s < 144; s++) sum += hn[key * 144 + s];
    __shared__ int tot[256];
    tot[key] = sum;
    __syncthreads();
    int excl = 0;
    for (int q = 0; q < key; q++) excl += tot[q];
    int run = excl;
    for (int s = 0; s < 144; s++) { int v = hn[key * 144 + s]; hn[key * 144 + s] = run; run += v; }
}

__global__ __launch_bounds__(256) void sort_scatter_k(const int* __restrict__ codes, const int* __restrict__ rank,
                                                      const int* __restrict__ hist, int* __restrict__ sidx,
                                                      int* __restrict__ undo)
{
    const int n = blockIdx.y, seg = blockIdx.x, tid = threadIdx.x;
    int j = seg * 256 + tid;
    int c = codes[(size_t)n * NJ + j];
    int dest = hist[(size_t)n * NJ + c * 144 + seg] + rank[(size_t)n * NJ + j];
    sidx[(size_t)n * NJ + dest] = j;
    undo[(size_t)n * NJ + j] = dest;
}

// ---------------------------------------------------------------- MFMA attention v3
// v2 overlaid Ks and P in one LDS buffer ("UN"), which forced P into registers (pbuf)
// across a barrier for cc>0. Combined with 77KB LDS (2 WG/CU fit), the compiler
// targeted 8 waves/EU -> capped arch-VGPRs at 64 -> spilled ~40 regs/thread to
// scratch (~330 MB of extra HBM write traffic per dispatch; WRITE_SIZE was 5.4x the
// logical output). v3: separate Qs/Ks/Ps buffers (LDS ~98KB -> 1 WG/CU, same as the
// measured residency anyway), pbuf eliminated (P written straight to LDS for ALL
// chunks), 6 barriers instead of 8, waves_per_eu pinned to 4 so the allocator uses
// the full 128-VGPR budget. P pad cols 144..159 are zeroed once and never overlaid.
#define QSTR 72     // Q/K row stride in shorts
#define PSTR 168    // P row stride in shorts
__global__ __launch_bounds__(1024, 4) __attribute__((amdgpu_waves_per_eu(4, 4))) void attn_mfma_k(
    const unsigned short* __restrict__ xmT_bf, const unsigned short* __restrict__ yaT,
    const float* __restrict__ ssq, const int* __restrict__ sidx,
    unsigned short* __restrict__ Osort, float* __restrict__ bs)
{
    __shared__ short Qs[144 * QSTR];
    __shared__ short Ks[144 * QSTR];
    __shared__ short Ps[144 * PSTR];
    __shared__ int   tIdx[432];
    __shared__ int   voff[432];
    __shared__ float nfs[432];
    __shared__ float qlen[432];
    __shared__ float lsum[144];
    __shared__ float linv[144];

    const int k = blockIdx.x, h = blockIdx.y, n = blockIdx.z;
    const int tid = threadIdx.x;
    const int w = tid >> 6, lane = tid & 63;
    const int lm = lane & 15, lq = lane >> 4;
    const size_t sbase = (size_t)n * NJ + (size_t)h * LL;

    if (tid < 432) {
        int cc = tid / CHK, rr = tid - cc * CHK;
        int c = (cc == 0) ? k : (cc == 1 ? (k + NCHUNK - 1) & (NCHUNK - 1) : (k + 1) & (NCHUNK - 1));
        int j = sidx[sbase + c * CHK + rr];
        int t = j % LL;
        tIdx[tid] = t;
        voff[tid] = t * (CHN * 2);
        float m = fmaxf(ssq[(size_t)n * LL + t], 5e-5f);
        float nf = rsqrtf(m);
        nfs[tid] = nf;
        qlen[tid] = m * nf;   // sqrt(m) = |q| clamped
    }
    __syncthreads();   // tIdx/voff/nfs/qlen ready

    // stage Q rows (raw bf16)
    for (int e = tid; e < 1152; e += 1024) {
        int r = e >> 3, j8 = e & 7;
        u16x8 v = *(const u16x8*)(xmT_bf + ((size_t)n * LL + tIdx[r]) * CC + j8 * 8);
        *(u16x8*)&Qs[r * QSTR + j8 * 8] = v;
    }
    // zero P pad columns 144..159 once; P writes only touch cols 0..143 and Ks never
    // overlays Ps, so the pad stays exactly 0 (NaN-safe under the lsum/PV reads).
    for (int e = tid; e < 2304; e += 1024) {
        int r = e >> 4, c = 144 + (e & 15);
        Ps[r * PSTR + c] = 0;
    }

    const char* vbase = (const char*)(yaT + (size_t)n * LL * CHN + w * 16 + lm);
    f32x4 accO[9];
#pragma unroll
    for (int mt = 0; mt < 9; mt++) accO[mt] = (f32x4){0.f, 0.f, 0.f, 0.f};
    f32x4 accL = (f32x4){0.f, 0.f, 0.f, 0.f};
    bf16x8 onesF, onesL;
#pragma unroll
    for (int i = 0; i < 8; i++) {
        onesF[i] = (short)0x3F80;
        onesL[i] = (lq < 2) ? (short)0x3F80 : (short)0;   // mask pad keys 144..159 (k-step 4, lq>=2)
    }

    for (int cc = 0; cc < 3; cc++) {
        const int c144 = cc * CHK;
        if (cc > 0) {
            // prior Ks readers (cc-1's QK) all completed before cc-1's "Ps ready" barrier
            for (int e = tid; e < 1152; e += 1024) {
                int r = e >> 3, j8 = e & 7;
                u16x8 v = *(const u16x8*)(xmT_bf + ((size_t)n * LL + tIdx[c144 + r]) * CC + j8 * 8);
                *(u16x8*)&Ks[r * QSTR + j8 * 8] = v;
            }
        }
        // V B-frag gathers from global — issued early, consumed after QK (latency hidden)
        bf16x8 vfrag[5];
#pragma unroll
        for (int ks = 0; ks < 5; ks++) {
            int kb = ks * 32 + lq * 8;
            if (kb < 144) {
                int4 o0 = *(const int4*)&voff[c144 + kb];
                int4 o1 = *(const int4*)&voff[c144 + kb + 4];
                vfrag[ks][0] = (short)*(const unsigned short*)(vbase + o0.x);
                vfrag[ks][1] = (short)*(const unsigned short*)(vbase + o0.y);
                vfrag[ks][2] = (short)*(const unsigned short*)(vbase + o0.z);
                vfrag[ks][3] = (short)*(const unsigned short*)(vbase + o0.w);
                vfrag[ks][4] = (short)*(const unsigned short*)(vbase + o1.x);
                vfrag[ks][5] = (short)*(const unsigned short*)(vbase + o1.y);
                vfrag[ks][6] = (short)*(const unsigned short*)(vbase + o1.z);
                vfrag[ks][7] = (short)*(const unsigned short*)(vbase + o1.w);
            } else {
                vfrag[ks] = (bf16x8){0, 0, 0, 0, 0, 0, 0, 0};
            }
        }
        // cc==0: Qs + Ps pad ready; cc>0: Ks ready AND prev chunk's Ps reads drained
        __syncthreads();

        // QK (B^T GEMM) + exp; raw scores post-scaled by key norm; P written straight to LDS
        const short* Bsrc = (cc == 0) ? Qs : Ks;
        for (int tt = w; tt < 81; tt += 16) {
            int mt = tt / 9, nt = tt - mt * 9;
            f32x4 c = {0.f, 0.f, 0.f, 0.f};
#pragma unroll
            for (int ks = 0; ks < 2; ks++) {
                bf16x8 a = *(const bf16x8*)&Qs[(mt * 16 + lm) * QSTR + ks * 32 + lq * 8];
                bf16x8 b = *(const bf16x8*)&Bsrc[(nt * 16 + lm) * QSTR + ks * 32 + lq * 8];
                c = __builtin_amdgcn_mfma_f32_16x16x32_bf16(a, b, c, 0, 0, 0);
            }
            float nfk = nfs[c144 + nt * 16 + lm];
#pragma unroll
            for (int r = 0; r < 4; r++) {
                int mrow = mt * 16 + lq * 4 + r;
                float p = __expf(fmaf(c[r], nfk, -qlen[mrow]));
                Ps[mrow * PSTR + nt * 16 + lm] = (short)f2b(p);
            }
        }
        __syncthreads();   // Ps ready (pad cols are permanent zeros)

        // lsum via ones-MFMA (waves 0..8, mt = w)
        if (w < 9) {
#pragma unroll
            for (int ks = 0; ks < 5; ks++) {
                bf16x8 a = *(const bf16x8*)&Ps[(w * 16 + lm) * PSTR + ks * 32 + lq * 8];
                accL = __builtin_amdgcn_mfma_f32_16x16x32_bf16(a, (ks == 4) ? onesL : onesF, accL, 0, 0, 0);
            }
        }
        // PV: 9 m-tiles, V frags in registers
#pragma unroll
        for (int mt = 0; mt < 9; mt++) {
            f32x4 c = accO[mt];
#pragma unroll
            for (int ks = 0; ks < 5; ks++) {
                bf16x8 a = *(const bf16x8*)&Ps[(mt * 16 + lm) * PSTR + ks * 32 + lq * 8];
                c = __builtin_amdgcn_mfma_f32_16x16x32_bf16(a, vfrag[ks], c, 0, 0, 0);
            }
            accO[mt] = c;
        }
    }

    if (w < 9 && lm == 0) {
#pragma unroll
        for (int r = 0; r < 4; r++) lsum[w * 16 + lq * 4 + r] = accL[r];
    }
    __syncthreads();
    if (tid < 144) {
        float l = lsum[tid];
        linv[tid] = 1.0f / l;
        bs[sbase + tIdx[tid]] = qlen[tid] + __logf(l);
    }
    __syncthreads();

#pragma unroll
    for (int mt = 0; mt < 9; mt++) {
        f32x4 c = accO[mt];
#pragma unroll
        for (int r = 0; r < 4; r++) {
            int mrow = mt * 16 + lq * 4 + r;
            Osort[(sbase + (size_t)k * CHK + mrow) * CHN + w * 16 + lm] = f2b(c[r] * linv[mrow]);
        }
    }
}

// ---------------------------------------------------------------- combine (4 hashes, inline softmax) + transpose + residual
__global__ __launch_bounds__(256) void combfin_k(
    const unsigned short* __restrict__ Osort, const float* __restrict__ bs,
    const int* __restrict__ undo, const float* __restrict__ inp, float* __restrict__ out)
{
    __shared__ float ac[32][260];
    __shared__ int   uS[4][32];
    __shared__ float pS[4][32];
    const int n = blockIdx.y;
    const int t0 = blockIdx.x * 32;
    const int tid = threadIdx.x;
    if (tid < 128) {
        int hh = tid >> 5, tt = tid & 31;
        size_t idx = (size_t)n * NJ + (size_t)hh * LL + t0 + tt;
        uS[hh][tt] = undo[idx];
        pS[hh][tt] = bs[idx];
    }
    __syncthreads();
    if (tid < 32) {
        float b0 = pS[0][tid], b1 = pS[1][tid], b2 = pS[2][tid], b3 = pS[3][tid];
        float mx = fmaxf(fmaxf(b0, b1), fmaxf(b2, b3));
        float e0 = __expf(b0 - mx), e1 = __expf(b1 - mx), e2 = __expf(b2 - mx), e3 = __expf(b3 - mx);
        float inv = 1.f / (e0 + e1 + e2 + e3);
        pS[0][tid] = e0 * inv; pS[1][tid] = e1 * inv; pS[2][tid] = e2 * inv; pS[3][tid] = e3 * inv;
    }
    __syncthreads();
    const int g = tid & 63, tq = tid >> 6;
    for (int tt8 = 0; tt8 < 8; tt8++) {
        int t = tq * 8 + tt8;
        float a0 = 0.f, a1 = 0.f, a2 = 0.f, a3 = 0.f;
#pragma unroll
        for (int hh = 0; hh < 4; hh++) {
            int row = uS[hh][t];
            float p = pS[hh][t];
            ushort4 u = *(const ushort4*)&Osort[((size_t)n * NJ + row) * CHN + g * 4];
            a0 = fmaf(p, b2f(u.x), a0);
            a1 = fmaf(p, b2f(u.y), a1);
            a2 = fmaf(p, b2f(u.z), a2);
            a3 = fmaf(p, b2f(u.w), a3);
        }
        *(float4*)&ac[t][g * 4] = make_float4(a0, a1, a2, a3);
    }
    __syncthreads();
    const int tp = tid & 31, er = tid >> 5;
    const float* inN = inp + (size_t)n * LL * CHN;
    float* outN = out + (size_t)n * LL * CHN;
    for (int it = 0; it < 32; it++) {
        int e = er + it * 8;
        size_t o = (size_t)e * LL + t0 + tp;
        outN[o] = ac[tp][e] * 0.1f + inN[o];
    }
}

// ---------------------------------------------------------------- launch
extern "C" void kernel_launch(void* const* d_in, const int* in_sizes, int n_in,
                              void* d_out, int out_size, void* d_ws, size_t ws_size,
                              hipStream_t stream)
{
    (void)in_sizes; (void)n_in; (void)out_size; (void)ws_size;
    const float* input   = (const float*)d_in[0];
    const float* w_match = (const float*)d_in[1];
    const float* b_match = (const float*)d_in[2];
    const float* w_asm   = (const float*)d_in[3];
    const float* b_asm   = (const float*)d_in[4];
    const float* rot     = (const float*)d_in[5];
    float* out = (float*)d_out;

    char* ws = (char*)d_ws;
    size_t off = 0;
    auto alloc = [&](size_t bytes) -> void* {
        void* p = ws + off;
        off += (bytes + 255) & ~(size_t)255;
        return p;
    };
    unsigned short* in_bf  = (unsigned short*)alloc((size_t)NB * LL * CHN * 2);
    unsigned short* wT_bf  = (unsigned short*)alloc((size_t)9 * CHN * CHN * 2);
    unsigned short* ya_bf  = (unsigned short*)alloc((size_t)NB * LL * CHN * 2);
    unsigned short* yaT    = (unsigned short*)alloc((size_t)NB * LL * CHN * 2);
    float* xm     = (float*)alloc((size_t)NB * LL * CC * 4);
    float* xmT    = (float*)alloc((size_t)NB * LL * CC * 4);
    unsigned short* xmT_bf = (unsigned short*)alloc((size_t)NB * LL * CC * 2);
    float* ssq    = (float*)alloc((size_t)NB * LL * 4);
    int*   codes  = (int*)  alloc((size_t)NB * NJ * 4);
    int*   rank   = (int*)  alloc((size_t)NB * NJ * 4);
    int*   hist   = (int*)  alloc((size_t)NB * NJ * 4);
    int*   sidx   = (int*)  alloc((size_t)NB * NJ * 4);
    int*   undo   = (int*)  alloc((size_t)NB * NJ * 4);
    float* bs     = (float*)alloc((size_t)NB * NJ * 4);
    unsigned short* Osort = (unsigned short*)alloc((size_t)NB * NJ * CHN * 2);

    // match path (fp32 — feeds hashing)
    conv3x3_k<<<dim3(144, 1, NB), 256, 0, stream>>>(input, w_match, b_match, xm, CC);
    transpose_k<<<dim3(288, 2, NB), 256, 0, stream>>>(xm, xmT, xmT_bf, CC, LL);
    // value path (bf16 MFMA)
    cvt_in_k<<<dim3(4608), 256, 0, stream>>>(input, in_bf);
    cvt_wT_k<<<dim3(8, 8, 9), 256, 0, stream>>>(w_asm, wT_bf);
    conv_mfma_k<<<dim3(72, 2, NB), 256, 0, stream>>>(in_bf, wT_bf, b_asm, ya_bf);
    transpose_bf_k<<<dim3(144, 4, NB), 256, 0, stream>>>(ya_bf, yaT);
    // hashing + sort
    hash_k<<<dim3(144), 256, 0, stream>>>(xmT, rot, codes, ssq);
    sort_hist_k<<<dim3(144, NB), 256, 0, stream>>>(codes, hist, rank);
    sort_scan_k<<<dim3(NB), 256, 0, stream>>>(hist);
    sort_scatter_k<<<dim3(144, NB), 256, 0, stream>>>(codes, rank, hist, sidx, undo);
    // attention + combine
    attn_mfma_k<<<dim3(NCHUNK, NHASH, NB), 1024, 0, stream>>>(xmT_bf, yaT, ssq, sidx, Osort, bs);
    combfin_k<<<dim3(288, NB), 256, 0, stream>>>(Osort, bs, undo, input, out);
}

// Round 2
// 581.889 us; speedup vs baseline: 1.2033x; 1.0200x over previous
//
#include <hip/hip_runtime.h>
#include <cstdint>
#include <cstddef>

#define NB 4
#define HH 96
#define WW 96
#define CHN 256
#define CC 64
#define LL 9216
#define NHASH 4
#define HBK 64
#define CHK 144
#define NCHUNK 64
#define NJ 36864   // NHASH * LL

typedef __attribute__((ext_vector_type(8))) short bf16x8;
typedef __attribute__((ext_vector_type(8))) unsigned short u16x8;
typedef __attribute__((ext_vector_type(4))) float f32x4;

__device__ __forceinline__ unsigned short f2b(float f) {
    unsigned int x = __float_as_uint(f);
    x += 0x7FFFu + ((x >> 16) & 1u);
    return (unsigned short)(x >> 16);
}
__device__ __forceinline__ float b2f(unsigned short u) {
    return __uint_as_float(((unsigned int)u) << 16);
}

// ---------------------------------------------------------------- conv 3x3 SAME (fp32 — match path, feeds hashing)
// v2: one block = one output row (96 px) x all 64 co. Input staged per 16-ci chunk
// WITH the 3-row halo, so all 9 taps read from one staged tile: 32 barriers total
// (was 288) and input fetched once per chunk (was once per tap, 9x). Weights for
// all 9 taps staged per chunk. Thread tile 6 px x 4 co; sliding 8-float window
// gives the 3 kx taps their operands from 4 float2 LDS reads. Ain px-stride 102:
// even (float2-aligned reads) and 4*102 % 32 != 0 (staging writes of the 4 ci of
// one float4 land in distinct banks).
__global__ __launch_bounds__(256, 2) void conv3x3_k(
    const float* __restrict__ in, const float* __restrict__ wgt,
    const float* __restrict__ bias, float* __restrict__ out, int CO)
{
    (void)CO;  // specialized: CO == 64
    __shared__ float Ain[3][16][102];   // [dy][ci][px+1]; col 0 and 97 are zero pads
    __shared__ float Wb[9][16][64];     // [tap][ci][co]
    const int tid = threadIdx.x;
    const int py  = blockIdx.x;
    const int n   = blockIdx.y;
    const int cg  = tid & 15;           // co group: co0 = cg*4
    const int pg  = tid >> 4;           // px group: px0 = pg*6
    const int px0 = pg * 6;
    const int co0 = cg * 4;
    const float* inN = in + (size_t)n * LL * CHN;

    // zero the horizontal pad columns once (stage writes only touch cols 1..96)
    if (tid < 96) {
        int dy = tid / 32, rem = tid & 31;
        int ci = rem >> 1, col = (rem & 1) ? 97 : 0;
        Ain[dy][ci][col] = 0.f;
    }

    float4 acc4[6];
#pragma unroll
    for (int j = 0; j < 6; j++) acc4[j] = make_float4(0.f, 0.f, 0.f, 0.f);

    for (int ci0 = 0; ci0 < 256; ci0 += 16) {
        // ---- stage A: 3 rows (halo) x 96 px x 16 ci
        for (int e = tid; e < 1152; e += 256) {
            int dy  = e / 384;
            int rem = e - dy * 384;
            int px  = rem >> 2;
            int ci4 = rem & 3;
            int sy  = py + dy - 1;
            float4 v = make_float4(0.f, 0.f, 0.f, 0.f);
            if ((unsigned)sy < (unsigned)HH)
                v = *(const float4*)(inN + (size_t)(sy * WW + px) * CHN + ci0 + ci4 * 4);
            Ain[dy][ci4 * 4 + 0][px + 1] = v.x;
            Ain[dy][ci4 * 4 + 1][px + 1] = v.y;
            Ain[dy][ci4 * 4 + 2][px + 1] = v.z;
            Ain[dy][ci4 * 4 + 3][px + 1] = v.w;
        }
        // ---- stage W: 9 taps x 16 ci x 64 co
        for (int e = tid; e < 2304; e += 256) {
            int tap = e >> 8;
            int rem = e & 255;
            int ci  = rem >> 4;
            int co4 = rem & 15;
            float4 v = *(const float4*)(wgt + (size_t)(tap * 256 + ci0 + ci) * 64 + co4 * 4);
            *(float4*)&Wb[tap][ci][co4 * 4] = v;
        }
        __syncthreads();   // tiles ready

        // ---- compute: 16 ci x 3 dy x 3 dx x (6 px x 4 co)
#pragma unroll 4
        for (int ci = 0; ci < 16; ci++) {
#pragma unroll
            for (int dy = 0; dy < 3; dy++) {
                const float* ar = &Ain[dy][ci][px0];
                float2 a01 = *(const float2*)(ar + 0);
                float2 a23 = *(const float2*)(ar + 2);
                float2 a45 = *(const float2*)(ar + 4);
                float2 a67 = *(const float2*)(ar + 6);
                float wnd[8] = {a01.x, a01.y, a23.x, a23.y, a45.x, a45.y, a67.x, a67.y};
#pragma unroll
                for (int dx = 0; dx < 3; dx++) {
                    float4 wv = *(const float4*)&Wb[dy * 3 + dx][ci][co0];
#pragma unroll
                    for (int j = 0; j < 6; j++) {
                        float a = wnd[dx + j];
                        acc4[j].x = fmaf(a, wv.x, acc4[j].x);
                        acc4[j].y = fmaf(a, wv.y, acc4[j].y);
                        acc4[j].z = fmaf(a, wv.z, acc4[j].z);
                        acc4[j].w = fmaf(a, wv.w, acc4[j].w);
                    }
                }
            }
        }
        __syncthreads();   // compute done before next chunk overwrites tiles
    }

    float4 bv = *(const float4*)(bias + co0);
    float* outN = out + (size_t)n * LL * 64;
#pragma unroll
    for (int j = 0; j < 6; j++) {
        int p = py * WW + px0 + j;
        float4 o;
        o.x = acc4[j].x + bv.x;
        o.y = acc4[j].y + bv.y;
        o.z = acc4[j].z + bv.z;
        o.w = acc4[j].w + bv.w;
        *(float4*)(outN + (size_t)p * 64 + co0) = o;
    }
}

// ---------------------------------------------------------------- fp32 transpose (match embedding) + bf16 copy
__global__ __launch_bounds__(256) void transpose_k(const float* __restrict__ in, float* __restrict__ out,
                                                   unsigned short* __restrict__ out_bf, int R, int Cc)
{
    __shared__ float tl[32][33];
    const int n = blockIdx.z;
    const size_t base = (size_t)n * R * Cc;
    int c0 = blockIdx.x * 32, r0 = blockIdx.y * 32;
    int tx = threadIdx.x & 31, ty0 = threadIdx.x >> 5;
#pragma unroll
    for (int i = 0; i < 32; i += 8)
        tl[ty0 + i][tx] = in[base + (size_t)(r0 + ty0 + i) * Cc + c0 + tx];
    __syncthreads();
#pragma unroll
    for (int i = 0; i < 32; i += 8) {
        float v = tl[tx][ty0 + i];
        size_t o = base + (size_t)(c0 + ty0 + i) * R + r0 + tx;
        out[o] = v;
        out_bf[o] = f2b(v);
    }
}

// ---------------------------------------------------------------- input fp32 -> bf16
__global__ __launch_bounds__(256) void cvt_in_k(const float* __restrict__ in, unsigned short* __restrict__ out)
{
    size_t g = ((size_t)blockIdx.x * 256 + threadIdx.x) * 8;
    float4 v0 = *(const float4*)(in + g);
    float4 v1 = *(const float4*)(in + g + 4);
    u16x8 o;
    o[0] = f2b(v0.x); o[1] = f2b(v0.y); o[2] = f2b(v0.z); o[3] = f2b(v0.w);
    o[4] = f2b(v1.x); o[5] = f2b(v1.y); o[6] = f2b(v1.z); o[7] = f2b(v1.w);
    *(u16x8*)(out + g) = o;
}

// ---------------------------------------------------------------- w_asm [tap][ci][co] fp32 -> wT [tap][co][ci] bf16
__global__ __launch_bounds__(256) void cvt_wT_k(const float* __restrict__ w, unsigned short* __restrict__ wT)
{
    __shared__ float tl[32][33];
    const int tap = blockIdx.z;
    const int c0 = blockIdx.x * 32;
    const int o0 = blockIdx.y * 32;
    const int tx = threadIdx.x & 31, ty0 = threadIdx.x >> 5;
#pragma unroll
    for (int i = 0; i < 32; i += 8)
        tl[ty0 + i][tx] = w[((size_t)tap * 256 + c0 + ty0 + i) * 256 + o0 + tx];
    __syncthreads();
#pragma unroll
    for (int i = 0; i < 32; i += 8)
        wT[((size_t)tap * 256 + o0 + ty0 + i) * 256 + c0 + tx] = f2b(tl[tx][ty0 + i]);
}

// ---------------------------------------------------------------- MFMA conv 3x3 (value path, bf16)
__global__ __launch_bounds__(256) void conv_mfma_k(
    const unsigned short* __restrict__ in_bf, const unsigned short* __restrict__ wT,
    const float* __restrict__ bias, unsigned short* __restrict__ ya_bf)
{
    __shared__ short As[128 * 32];
    __shared__ short Bs[128 * 32];
    const int n = blockIdx.z, p0 = blockIdx.x * 128, co0 = blockIdx.y * 128;
    const int tid = threadIdx.x;
    const int w = tid >> 6, wr = w >> 1, wc = w & 1;
    const int lane = tid & 63, lm = lane & 15, lq = lane >> 4;
    const int r = tid >> 1, hf = tid & 1;
    const int p = p0 + r, py = p / WW, px = p % WW;
    const unsigned short* inN = in_bf + (size_t)n * LL * CHN;

    f32x4 acc[4][4];
#pragma unroll
    for (int a = 0; a < 4; a++)
#pragma unroll
        for (int b = 0; b < 4; b++) acc[a][b] = (f32x4){0.f, 0.f, 0.f, 0.f};

    for (int tap = 0; tap < 9; tap++) {
        const int ky = tap / 3, kx = tap - ky * 3;
        const int sy = py + ky - 1, sx = px + kx - 1;
        const bool valid = ((unsigned)sy < HH) && ((unsigned)sx < WW);
        const unsigned short* asrc = inN + (size_t)(sy * WW + sx) * CHN + hf * 16;
        const unsigned short* bsrc = wT + ((size_t)tap * 256 + co0 + r) * 256 + hf * 16;
        for (int ci0 = 0; ci0 < 256; ci0 += 32) {
            u16x8 av0 = (u16x8){0,0,0,0,0,0,0,0}, av1 = (u16x8){0,0,0,0,0,0,0,0};
            if (valid) {
                av0 = *(const u16x8*)(asrc + ci0);
                av1 = *(const u16x8*)(asrc + ci0 + 8);
            }
            u16x8 bv0 = *(const u16x8*)(bsrc + ci0);
            u16x8 bv1 = *(const u16x8*)(bsrc + ci0 + 8);
            __syncthreads();
            *(u16x8*)&As[r * 32 + hf * 16]     = av0;
            *(u16x8*)&As[r * 32 + hf * 16 + 8] = av1;
            *(u16x8*)&Bs[r * 32 + hf * 16]     = bv0;
            *(u16x8*)&Bs[r * 32 + hf * 16 + 8] = bv1;
            __syncthreads();
            bf16x8 af[4], bf[4];
#pragma unroll
            for (int mt = 0; mt < 4; mt++)
                af[mt] = *(const bf16x8*)&As[(wr * 64 + mt * 16 + lm) * 32 + lq * 8];
#pragma unroll
            for (int nt = 0; nt < 4; nt++)
                bf[nt] = *(const bf16x8*)&Bs[(wc * 64 + nt * 16 + lm) * 32 + lq * 8];
#pragma unroll
            for (int mt = 0; mt < 4; mt++)
#pragma unroll
                for (int nt = 0; nt < 4; nt++)
                    acc[mt][nt] = __builtin_amdgcn_mfma_f32_16x16x32_bf16(af[mt], bf[nt], acc[mt][nt], 0, 0, 0);
        }
    }
    float bv[4];
#pragma unroll
    for (int nt = 0; nt < 4; nt++) bv[nt] = bias[co0 + wc * 64 + nt * 16 + lm];
#pragma unroll
    for (int mt = 0; mt < 4; mt++) {
#pragma unroll
        for (int r4 = 0; r4 < 4; r4++) {
            int row = p0 + wr * 64 + mt * 16 + lq * 4 + r4;
            unsigned short* od = ya_bf + ((size_t)n * LL + row) * CHN + co0 + wc * 64;
#pragma unroll
            for (int nt = 0; nt < 4; nt++)
                od[nt * 16 + lm] = f2b(acc[mt][nt][r4] + bv[nt]);
        }
    }
}

// ---------------------------------------------------------------- bf16 transpose: ya_bf (viewed [256][9216]) -> yaT [9216][256]
__global__ __launch_bounds__(256) void transpose_bf_k(const unsigned short* __restrict__ in,
                                                      unsigned short* __restrict__ out)
{
    __shared__ unsigned short tl[64][65];
    const int n = blockIdx.z;
    const size_t base = (size_t)n * LL * CHN;
    const int t0 = blockIdx.x * 64, e0 = blockIdx.y * 64;
    const int tx = threadIdx.x & 63, ty0 = threadIdx.x >> 6;
#pragma unroll
    for (int i = 0; i < 16; i++) {
        int row = ty0 + i * 4;
        tl[row][tx] = in[base + (size_t)(e0 + row) * LL + t0 + tx];
    }
    __syncthreads();
#pragma unroll
    for (int i = 0; i < 16; i++) {
        int row = ty0 + i * 4;
        out[base + (size_t)(t0 + row) * CHN + e0 + tx] = tl[tx][row];
    }
}

// ---------------------------------------------------------------- hashing: codes + squared norms (fp32!)
__global__ __launch_bounds__(256) void hash_k(const float* __restrict__ xmT, const float* __restrict__ rot,
                                              int* __restrict__ codes, float* __restrict__ ssq)
{
    __shared__ float rs[128 * 68];   // [hi][f], stride 68
    for (int e = threadIdx.x; e < 8192; e += 256) {
        int hi = e >> 6, f = e & 63;
        rs[hi * 68 + f] = rot[f * 128 + hi];
    }
    __syncthreads();
    int g = blockIdx.x * 256 + threadIdx.x;
    int n = g / LL, t = g % LL;
    float4 x4[16];
    const float* src = xmT + (size_t)g * CC;
#pragma unroll
    for (int f4 = 0; f4 < 16; f4++) x4[f4] = *(const float4*)(src + f4 * 4);
    float ss = 0.f;
#pragma unroll
    for (int f4 = 0; f4 < 16; f4++)
        ss += x4[f4].x * x4[f4].x + x4[f4].y * x4[f4].y + x4[f4].z * x4[f4].z + x4[f4].w * x4[f4].w;
    ssq[g] = ss;
    for (int h = 0; h < NHASH; h++) {
        float bp = -1e30f, bn = -1e30f;
        int ip = 0, inn = 0;
        for (int i = 0; i < 32; i++) {
            const float* rr = &rs[(h * 32 + i) * 68];
            float d0 = 0.f, d1 = 0.f, d2 = 0.f, d3 = 0.f;
#pragma unroll
            for (int f4 = 0; f4 < 16; f4++) {
                float4 r4 = *(const float4*)(rr + f4 * 4);
                d0 = fmaf(x4[f4].x, r4.x, d0);
                d1 = fmaf(x4[f4].y, r4.y, d1);
                d2 = fmaf(x4[f4].z, r4.z, d2);
                d3 = fmaf(x4[f4].w, r4.w, d3);
            }
            float d = (d0 + d1) + (d2 + d3);
            if (d > bp) { bp = d; ip = i; }
            if (-d > bn) { bn = -d; inn = i; }
        }
        int code = (bp >= bn) ? ip : (32 + inn);
        codes[(size_t)n * NJ + h * LL + t] = code + h * HBK;
    }
}

// ---------------------------------------------------------------- stable counting sort (256 buckets)
__global__ __launch_bounds__(256) void sort_hist_k(const int* __restrict__ codes, int* __restrict__ hist,
                                                   int* __restrict__ rank)
{
    __shared__ int lc[256];
    __shared__ int lh[256];
    const int n = blockIdx.y, seg = blockIdx.x, tid = threadIdx.x;
    int j = seg * 256 + tid;
    int c = codes[(size_t)n * NJ + j];
    lc[tid] = c;
    lh[tid] = 0;
    __syncthreads();
    int r = 0;
    for (int q = 0; q < tid; q++) r += (lc[q] == c) ? 1 : 0;
    atomicAdd(&lh[c], 1);
    __syncthreads();
    rank[(size_t)n * NJ + j] = r;
    hist[(size_t)n * NJ + tid * 144 + seg] = lh[tid];
}

__global__ __launch_bounds__(256) void sort_scan_k(int* __restrict__ hist)
{
    const int n = blockIdx.x;
    const int key = threadIdx.x;
    int* hn = hist + (size_t)n * NJ;
    int sum = 0;
    for (int s = 0; s < 144; s++) sum += hn[key * 144 + s];
    __shared__ int tot[256];
    tot[key] = sum;
    __syncthreads();
    int excl = 0;
    for (int q = 0; q < key; q++) excl += tot[q];
    int run = excl;
    for (int s = 0; s < 144; s++) { int v = hn[key * 144 + s]; hn[key * 144 + s] = run; run += v; }
}

__global__ __launch_bounds__(256) void sort_scatter_k(const int* __restrict__ codes, const int* __restrict__ rank,
                                                      const int* __restrict__ hist, int* __restrict__ sidx,
                                                      int* __restrict__ undo)
{
    const int n = blockIdx.y, seg = blockIdx.x, tid = threadIdx.x;
    int j = seg * 256 + tid;
    int c = codes[(size_t)n * NJ + j];
    int dest = hist[(size_t)n * NJ + c * 144 + seg] + rank[(size_t)n * NJ + j];
    sidx[(size_t)n * NJ + dest] = j;
    undo[(size_t)n * NJ + j] = dest;
}

// ---------------------------------------------------------------- MFMA attention v3
// Separate Qs/Ks/Ps buffers (no overlay) -> P written straight to LDS for all
// chunks, no pbuf across barriers, no scratch spills. waves_per_eu pinned to 4.
#define QSTR 72     // Q/K row stride in shorts
#define PSTR 168    // P row stride in shorts
__global__ __launch_bounds__(1024, 4) __attribute__((amdgpu_waves_per_eu(4, 4))) void attn_mfma_k(
    const unsigned short* __restrict__ xmT_bf, const unsigned short* __restrict__ yaT,
    const float* __restrict__ ssq, const int* __restrict__ sidx,
    unsigned short* __restrict__ Osort, float* __restrict__ bs)
{
    __shared__ short Qs[144 * QSTR];
    __shared__ short Ks[144 * QSTR];
    __shared__ short Ps[144 * PSTR];
    __shared__ int   tIdx[432];
    __shared__ int   voff[432];
    __shared__ float nfs[432];
    __shared__ float qlen[432];
    __shared__ float lsum[144];
    __shared__ float linv[144];

    const int k = blockIdx.x, h = blockIdx.y, n = blockIdx.z;
    const int tid = threadIdx.x;
    const int w = tid >> 6, lane = tid & 63;
    const int lm = lane & 15, lq = lane >> 4;
    const size_t sbase = (size_t)n * NJ + (size_t)h * LL;

    if (tid < 432) {
        int cc = tid / CHK, rr = tid - cc * CHK;
        int c = (cc == 0) ? k : (cc == 1 ? (k + NCHUNK - 1) & (NCHUNK - 1) : (k + 1) & (NCHUNK - 1));
        int j = sidx[sbase + c * CHK + rr];
        int t = j % LL;
        tIdx[tid] = t;
        voff[tid] = t * (CHN * 2);
        float m = fmaxf(ssq[(size_t)n * LL + t], 5e-5f);
        float nf = rsqrtf(m);
        nfs[tid] = nf;
        qlen[tid] = m * nf;   // sqrt(m) = |q| clamped
    }
    __syncthreads();   // tIdx/voff/nfs/qlen ready

    // stage Q rows (raw bf16)
    for (int e = tid; e < 1152; e += 1024) {
        int r = e >> 3, j8 = e & 7;
        u16x8 v = *(const u16x8*)(xmT_bf + ((size_t)n * LL + tIdx[r]) * CC + j8 * 8);
        *(u16x8*)&Qs[r * QSTR + j8 * 8] = v;
    }
    // zero P pad columns 144..159 once; P writes only touch cols 0..143 and Ks never
    // overlays Ps, so the pad stays exactly 0 (NaN-safe under the lsum/PV reads).
    for (int e = tid; e < 2304; e += 1024) {
        int r = e >> 4, c = 144 + (e & 15);
        Ps[r * PSTR + c] = 0;
    }

    const char* vbase = (const char*)(yaT + (size_t)n * LL * CHN + w * 16 + lm);
    f32x4 accO[9];
#pragma unroll
    for (int mt = 0; mt < 9; mt++) accO[mt] = (f32x4){0.f, 0.f, 0.f, 0.f};
    f32x4 accL = (f32x4){0.f, 0.f, 0.f, 0.f};
    bf16x8 onesF, onesL;
#pragma unroll
    for (int i = 0; i < 8; i++) {
        onesF[i] = (short)0x3F80;
        onesL[i] = (lq < 2) ? (short)0x3F80 : (short)0;   // mask pad keys 144..159 (k-step 4, lq>=2)
    }

    for (int cc = 0; cc < 3; cc++) {
        const int c144 = cc * CHK;
        if (cc > 0) {
            // prior Ks readers (cc-1's QK) all completed before cc-1's "Ps ready" barrier
            for (int e = tid; e < 1152; e += 1024) {
                int r = e >> 3, j8 = e & 7;
                u16x8 v = *(const u16x8*)(xmT_bf + ((size_t)n * LL + tIdx[c144 + r]) * CC + j8 * 8);
                *(u16x8*)&Ks[r * QSTR + j8 * 8] = v;
            }
        }
        // V B-frag gathers from global — issued early, consumed after QK (latency hidden)
        bf16x8 vfrag[5];
#pragma unroll
        for (int ks = 0; ks < 5; ks++) {
            int kb = ks * 32 + lq * 8;
            if (kb < 144) {
                int4 o0 = *(const int4*)&voff[c144 + kb];
                int4 o1 = *(const int4*)&voff[c144 + kb + 4];
                vfrag[ks][0] = (short)*(const unsigned short*)(vbase + o0.x);
                vfrag[ks][1] = (short)*(const unsigned short*)(vbase + o0.y);
                vfrag[ks][2] = (short)*(const unsigned short*)(vbase + o0.z);
                vfrag[ks][3] = (short)*(const unsigned short*)(vbase + o0.w);
                vfrag[ks][4] = (short)*(const unsigned short*)(vbase + o1.x);
                vfrag[ks][5] = (short)*(const unsigned short*)(vbase + o1.y);
                vfrag[ks][6] = (short)*(const unsigned short*)(vbase + o1.z);
                vfrag[ks][7] = (short)*(const unsigned short*)(vbase + o1.w);
            } else {
                vfrag[ks] = (bf16x8){0, 0, 0, 0, 0, 0, 0, 0};
            }
        }
        // cc==0: Qs + Ps pad ready; cc>0: Ks ready AND prev chunk's Ps reads drained
        __syncthreads();

        // QK (B^T GEMM) + exp; raw scores post-scaled by key norm; P written straight to LDS
        const short* Bsrc = (cc == 0) ? Qs : Ks;
        for (int tt = w; tt < 81; tt += 16) {
            int mt = tt / 9, nt = tt - mt * 9;
            f32x4 c = {0.f, 0.f, 0.f, 0.f};
#pragma unroll
            for (int ks = 0; ks < 2; ks++) {
                bf16x8 a = *(const bf16x8*)&Qs[(mt * 16 + lm) * QSTR + ks * 32 + lq * 8];
                bf16x8 b = *(const bf16x8*)&Bsrc[(nt * 16 + lm) * QSTR + ks * 32 + lq * 8];
                c = __builtin_amdgcn_mfma_f32_16x16x32_bf16(a, b, c, 0, 0, 0);
            }
            float nfk = nfs[c144 + nt * 16 + lm];
#pragma unroll
            for (int r = 0; r < 4; r++) {
                int mrow = mt * 16 + lq * 4 + r;
                float p = __expf(fmaf(c[r], nfk, -qlen[mrow]));
                Ps[mrow * PSTR + nt * 16 + lm] = (short)f2b(p);
            }
        }
        __syncthreads();   // Ps ready (pad cols are permanent zeros)

        // lsum via ones-MFMA (waves 0..8, mt = w)
        if (w < 9) {
#pragma unroll
            for (int ks = 0; ks < 5; ks++) {
                bf16x8 a = *(const bf16x8*)&Ps[(w * 16 + lm) * PSTR + ks * 32 + lq * 8];
                accL = __builtin_amdgcn_mfma_f32_16x16x32_bf16(a, (ks == 4) ? onesL : onesF, accL, 0, 0, 0);
            }
        }
        // PV: 9 m-tiles, V frags in registers
#pragma unroll
        for (int mt = 0; mt < 9; mt++) {
            f32x4 c = accO[mt];
#pragma unroll
            for (int ks = 0; ks < 5; ks++) {
                bf16x8 a = *(const bf16x8*)&Ps[(mt * 16 + lm) * PSTR + ks * 32 + lq * 8];
                c = __builtin_amdgcn_mfma_f32_16x16x32_bf16(a, vfrag[ks], c, 0, 0, 0);
            }
            accO[mt] = c;
        }
    }

    if (w < 9 && lm == 0) {
#pragma unroll
        for (int r = 0; r < 4; r++) lsum[w * 16 + lq * 4 + r] = accL[r];
    }
    __syncthreads();
    if (tid < 144) {
        float l = lsum[tid];
        linv[tid] = 1.0f / l;
        bs[sbase + tIdx[tid]] = qlen[tid] + __logf(l);
    }
    __syncthreads();

#pragma unroll
    for (int mt = 0; mt < 9; mt++) {
        f32x4 c = accO[mt];
#pragma unroll
        for (int r = 0; r < 4; r++) {
            int mrow = mt * 16 + lq * 4 + r;
            Osort[(sbase + (size_t)k * CHK + mrow) * CHN + w * 16 + lm] = f2b(c[r] * linv[mrow]);
        }
    }
}

// ---------------------------------------------------------------- combine (4 hashes, inline softmax) + transpose + residual
__global__ __launch_bounds__(256) void combfin_k(
    const unsigned short* __restrict__ Osort, const float* __restrict__ bs,
    const int* __restrict__ undo, const float* __restrict__ inp, float* __restrict__ out)
{
    __shared__ float ac[32][260];
    __shared__ int   uS[4][32];
    __shared__ float pS[4][32];
    const int n = blockIdx.y;
    const int t0 = blockIdx.x * 32;
    const int tid = threadIdx.x;
    if (tid < 128) {
        int hh = tid >> 5, tt = tid & 31;
        size_t idx = (size_t)n * NJ + (size_t)hh * LL + t0 + tt;
        uS[hh][tt] = undo[idx];
        pS[hh][tt] = bs[idx];
    }
    __syncthreads();
    if (tid < 32) {
        float b0 = pS[0][tid], b1 = pS[1][tid], b2 = pS[2][tid], b3 = pS[3][tid];
        float mx = fmaxf(fmaxf(b0, b1), fmaxf(b2, b3));
        float e0 = __expf(b0 - mx), e1 = __expf(b1 - mx), e2 = __expf(b2 - mx), e3 = __expf(b3 - mx);
        float inv = 1.f / (e0 + e1 + e2 + e3);
        pS[0][tid] = e0 * inv; pS[1][tid] = e1 * inv; pS[2][tid] = e2 * inv; pS[3][tid] = e3 * inv;
    }
    __syncthreads();
    const int g = tid & 63, tq = tid >> 6;
    for (int tt8 = 0; tt8 < 8; tt8++) {
        int t = tq * 8 + tt8;
        float a0 = 0.f, a1 = 0.f, a2 = 0.f, a3 = 0.f;
#pragma unroll
        for (int hh = 0; hh < 4; hh++) {
            int row = uS[hh][t];
            float p = pS[hh][t];
            ushort4 u = *(const ushort4*)&Osort[((size_t)n * NJ + row) * CHN + g * 4];
            a0 = fmaf(p, b2f(u.x), a0);
            a1 = fmaf(p, b2f(u.y), a1);
            a2 = fmaf(p, b2f(u.z), a2);
            a3 = fmaf(p, b2f(u.w), a3);
        }
        *(float4*)&ac[t][g * 4] = make_float4(a0, a1, a2, a3);
    }
    __syncthreads();
    const int tp = tid & 31, er = tid >> 5;
    const float* inN = inp + (size_t)n * LL * CHN;
    float* outN = out + (size_t)n * LL * CHN;
    for (int it = 0; it < 32; it++) {
        int e = er + it * 8;
        size_t o = (size_t)e * LL + t0 + tp;
        outN[o] = ac[tp][e] * 0.1f + inN[o];
    }
}

// ---------------------------------------------------------------- launch
extern "C" void kernel_launch(void* const* d_in, const int* in_sizes, int n_in,
                              void* d_out, int out_size, void* d_ws, size_t ws_size,
                              hipStream_t stream)
{
    (void)in_sizes; (void)n_in; (void)out_size; (void)ws_size;
    const float* input   = (const float*)d_in[0];
    const float* w_match = (const float*)d_in[1];
    const float* b_match = (const float*)d_in[2];
    const float* w_asm   = (const float*)d_in[3];
    const float* b_asm   = (const float*)d_in[4];
    const float* rot     = (const float*)d_in[5];
    float* out = (float*)d_out;

    char* ws = (char*)d_ws;
    size_t off = 0;
    auto alloc = [&](size_t bytes) -> void* {
        void* p = ws + off;
        off += (bytes + 255) & ~(size_t)255;
        return p;
    };
    unsigned short* in_bf  = (unsigned short*)alloc((size_t)NB * LL * CHN * 2);
    unsigned short* wT_bf  = (unsigned short*)alloc((size_t)9 * CHN * CHN * 2);
    unsigned short* ya_bf  = (unsigned short*)alloc((size_t)NB * LL * CHN * 2);
    unsigned short* yaT    = (unsigned short*)alloc((size_t)NB * LL * CHN * 2);
    float* xm     = (float*)alloc((size_t)NB * LL * CC * 4);
    float* xmT    = (float*)alloc((size_t)NB * LL * CC * 4);
    unsigned short* xmT_bf = (unsigned short*)alloc((size_t)NB * LL * CC * 2);
    float* ssq    = (float*)alloc((size_t)NB * LL * 4);
    int*   codes  = (int*)  alloc((size_t)NB * NJ * 4);
    int*   rank   = (int*)  alloc((size_t)NB * NJ * 4);
    int*   hist   = (int*)  alloc((size_t)NB * NJ * 4);
    int*   sidx   = (int*)  alloc((size_t)NB * NJ * 4);
    int*   undo   = (int*)  alloc((size_t)NB * NJ * 4);
    float* bs     = (float*)alloc((size_t)NB * NJ * 4);
    unsigned short* Osort = (unsigned short*)alloc((size_t)NB * NJ * CHN * 2);

    // match path (fp32 — feeds hashing)
    conv3x3_k<<<dim3(96, NB), 256, 0, stream>>>(input, w_match, b_match, xm, CC);
    transpose_k<<<dim3(288, 2, NB), 256, 0, stream>>>(xm, xmT, xmT_bf, CC, LL);
    // value path (bf16 MFMA)
    cvt_in_k<<<dim3(4608), 256, 0, stream>>>(input, in_bf);
    cvt_wT_k<<<dim3(8, 8, 9), 256, 0, stream>>>(w_asm, wT_bf);
    conv_mfma_k<<<dim3(72, 2, NB), 256, 0, stream>>>(in_bf, wT_bf, b_asm, ya_bf);
    transpose_bf_k<<<dim3(144, 4, NB), 256, 0, stream>>>(ya_bf, yaT);
    // hashing + sort
    hash_k<<<dim3(144), 256, 0, stream>>>(xmT, rot, codes, ssq);
    sort_hist_k<<<dim3(144, NB), 256, 0, stream>>>(codes, hist, rank);
    sort_scan_k<<<dim3(NB), 256, 0, stream>>>(hist);
    sort_scatter_k<<<dim3(144, NB), 256, 0, stream>>>(codes, rank, hist, sidx, undo);
    // attention + combine
    attn_mfma_k<<<dim3(NCHUNK, NHASH, NB), 1024, 0, stream>>>(xmT_bf, yaT, ssq, sidx, Osort, bs);
    combfin_k<<<dim3(288, NB), 256, 0, stream>>>(Osort, bs, undo, input, out);
}

// Round 3
// 496.999 us; speedup vs baseline: 1.4088x; 1.1708x over previous
//
#include <hip/hip_runtime.h>
#include <cstdint>
#include <cstddef>

#define NB 4
#define HH 96
#define WW 96
#define CHN 256
#define CC 64
#define LL 9216
#define NHASH 4
#define HBK 64
#define CHK 144
#define NCHUNK 64
#define NJ 36864   // NHASH * LL

typedef __attribute__((ext_vector_type(8))) short bf16x8;
typedef __attribute__((ext_vector_type(8))) unsigned short u16x8;
typedef __attribute__((ext_vector_type(4))) float f32x4;

__device__ __forceinline__ unsigned short f2b(float f) {
    unsigned int x = __float_as_uint(f);
    x += 0x7FFFu + ((x >> 16) & 1u);
    return (unsigned short)(x >> 16);
}
__device__ __forceinline__ float b2f(unsigned short u) {
    return __uint_as_float(((unsigned int)u) << 16);
}

// ---------------------------------------------------------------- input fp32 -> bf16 hi + bf16 lo residual
// hi = RNE bf16 of x (identical to the old in_bf, still feeds the value-path conv);
// lo = RNE bf16 of (x - hi). x ~= hi + lo to ~16 mantissa bits.
__global__ __launch_bounds__(256) void cvt_in_hilo_k(const float* __restrict__ in,
                                                     unsigned short* __restrict__ hi,
                                                     unsigned short* __restrict__ lo)
{
    size_t g = ((size_t)blockIdx.x * 256 + threadIdx.x) * 8;
    float4 v0 = *(const float4*)(in + g);
    float4 v1 = *(const float4*)(in + g + 4);
    float xs[8] = {v0.x, v0.y, v0.z, v0.w, v1.x, v1.y, v1.z, v1.w};
    u16x8 h, l;
#pragma unroll
    for (int i = 0; i < 8; i++) {
        unsigned short hv = f2b(xs[i]);
        h[i] = hv;
        l[i] = f2b(xs[i] - b2f(hv));
    }
    *(u16x8*)(hi + g) = h;
    *(u16x8*)(lo + g) = l;
}

// ---------------------------------------------------------------- w_match [tap][ci][64] fp32 -> wmT [tap][co=64][ci=256] bf16 hi/lo
__global__ __launch_bounds__(256) void cvt_wm_hilo_k(const float* __restrict__ w,
                                                     unsigned short* __restrict__ hiT,
                                                     unsigned short* __restrict__ loT)
{
    __shared__ float tl[32][33];
    const int tap = blockIdx.z;
    const int c0 = blockIdx.x * 32;   // ci
    const int o0 = blockIdx.y * 32;   // co (64 total -> gridDim.y = 2)
    const int tx = threadIdx.x & 31, ty0 = threadIdx.x >> 5;
#pragma unroll
    for (int i = 0; i < 32; i += 8)
        tl[ty0 + i][tx] = w[((size_t)tap * 256 + c0 + ty0 + i) * 64 + o0 + tx];
    __syncthreads();
#pragma unroll
    for (int i = 0; i < 32; i += 8) {
        float v = tl[tx][ty0 + i];
        unsigned short h = f2b(v);
        size_t o = ((size_t)tap * 64 + o0 + ty0 + i) * 256 + c0 + tx;
        hiT[o] = h;
        loT[o] = f2b(v - b2f(h));
    }
}

// ---------------------------------------------------------------- MFMA conv 3x3 (match path, split-bf16 ~fp32 precision)
// Replaces the fp32 VALU conv (structural floor 69 us, measured 210 us, latency-bound
// at <2 blocks/CU). x = xh + xl, w = wh + wl; conv(x,w) ~= xh*wh + xh*wl + xl*wh
// (lo*lo term ~2^-18 relative, dropped). 3x the MFMA work of a plain bf16 conv but
// on the 2.4 PF matrix pipe instead of the 157 TF vector pipe. Tile 128 px x 64 co,
// 4 waves (each 32 px x 64 co). ASTR=40 pads the fragment rows: 16-lane b128 reads
// at 80B stride hit 2-way bank aliasing (free) instead of 8-way at 64B.
#define ASTR 40
__global__ __launch_bounds__(256, 2) void conv_match_mfma_k(
    const unsigned short* __restrict__ in_hi, const unsigned short* __restrict__ in_lo,
    const unsigned short* __restrict__ wmT_hi, const unsigned short* __restrict__ wmT_lo,
    const float* __restrict__ bias, float* __restrict__ xm)
{
    __shared__ short Ah[128 * ASTR], Al[128 * ASTR];
    __shared__ short Bh[64 * ASTR],  Bl[64 * ASTR];
    const int n = blockIdx.z, p0 = blockIdx.x * 128;
    const int tid = threadIdx.x;
    const int w = tid >> 6;
    const int lane = tid & 63, lm = lane & 15, lq = lane >> 4;
    const int r = tid >> 1, hf = tid & 1;            // A staging: row 0..127, 16-ci half
    const int p = p0 + r, py = p / WW, px = p % WW;
    const int rb = tid >> 2, cb = (tid & 3) * 8;     // B staging: row 0..63, 8-ci group
    const unsigned short* hiN = in_hi + (size_t)n * LL * CHN;
    const unsigned short* loN = in_lo + (size_t)n * LL * CHN;

    f32x4 acc[2][4];
#pragma unroll
    for (int a = 0; a < 2; a++)
#pragma unroll
        for (int b = 0; b < 4; b++) acc[a][b] = (f32x4){0.f, 0.f, 0.f, 0.f};

    for (int tap = 0; tap < 9; tap++) {
        const int ky = tap / 3, kx = tap - ky * 3;
        const int sy = py + ky - 1, sx = px + kx - 1;
        const bool valid = ((unsigned)sy < HH) && ((unsigned)sx < WW);
        const unsigned short* ah = hiN + (size_t)(sy * WW + sx) * CHN + hf * 16;
        const unsigned short* al = loN + (size_t)(sy * WW + sx) * CHN + hf * 16;
        const unsigned short* bh = wmT_hi + ((size_t)tap * 64 + rb) * 256 + cb;
        const unsigned short* bl = wmT_lo + ((size_t)tap * 64 + rb) * 256 + cb;
        for (int ci0 = 0; ci0 < 256; ci0 += 32) {
            u16x8 avh0 = (u16x8){0,0,0,0,0,0,0,0}, avh1 = (u16x8){0,0,0,0,0,0,0,0};
            u16x8 avl0 = (u16x8){0,0,0,0,0,0,0,0}, avl1 = (u16x8){0,0,0,0,0,0,0,0};
            if (valid) {
                avh0 = *(const u16x8*)(ah + ci0);
                avh1 = *(const u16x8*)(ah + ci0 + 8);
                avl0 = *(const u16x8*)(al + ci0);
                avl1 = *(const u16x8*)(al + ci0 + 8);
            }
            u16x8 bvh = *(const u16x8*)(bh + ci0);
            u16x8 bvl = *(const u16x8*)(bl + ci0);
            __syncthreads();
            *(u16x8*)&Ah[r * ASTR + hf * 16]     = avh0;
            *(u16x8*)&Ah[r * ASTR + hf * 16 + 8] = avh1;
            *(u16x8*)&Al[r * ASTR + hf * 16]     = avl0;
            *(u16x8*)&Al[r * ASTR + hf * 16 + 8] = avl1;
            *(u16x8*)&Bh[rb * ASTR + cb] = bvh;
            *(u16x8*)&Bl[rb * ASTR + cb] = bvl;
            __syncthreads();
            bf16x8 afh[2], afl[2], bfh[4], bfl[4];
#pragma unroll
            for (int mt = 0; mt < 2; mt++) {
                afh[mt] = *(const bf16x8*)&Ah[(w * 32 + mt * 16 + lm) * ASTR + lq * 8];
                afl[mt] = *(const bf16x8*)&Al[(w * 32 + mt * 16 + lm) * ASTR + lq * 8];
            }
#pragma unroll
            for (int nt = 0; nt < 4; nt++) {
                bfh[nt] = *(const bf16x8*)&Bh[(nt * 16 + lm) * ASTR + lq * 8];
                bfl[nt] = *(const bf16x8*)&Bl[(nt * 16 + lm) * ASTR + lq * 8];
            }
#pragma unroll
            for (int mt = 0; mt < 2; mt++)
#pragma unroll
                for (int nt = 0; nt < 4; nt++) {
                    acc[mt][nt] = __builtin_amdgcn_mfma_f32_16x16x32_bf16(afh[mt], bfh[nt], acc[mt][nt], 0, 0, 0);
                    acc[mt][nt] = __builtin_amdgcn_mfma_f32_16x16x32_bf16(afh[mt], bfl[nt], acc[mt][nt], 0, 0, 0);
                    acc[mt][nt] = __builtin_amdgcn_mfma_f32_16x16x32_bf16(afl[mt], bfh[nt], acc[mt][nt], 0, 0, 0);
                }
        }
    }
    float bvv[4];
#pragma unroll
    for (int nt = 0; nt < 4; nt++) bvv[nt] = bias[nt * 16 + lm];
    float* outN = xm + (size_t)n * LL * 64;
#pragma unroll
    for (int mt = 0; mt < 2; mt++)
#pragma unroll
        for (int r4 = 0; r4 < 4; r4++) {
            int row = p0 + w * 32 + mt * 16 + lq * 4 + r4;
            float* od = outN + (size_t)row * 64;
#pragma unroll
            for (int nt = 0; nt < 4; nt++)
                od[nt * 16 + lm] = acc[mt][nt][r4] + bvv[nt];
        }
}

// ---------------------------------------------------------------- fp32 transpose (match embedding) + bf16 copy
__global__ __launch_bounds__(256) void transpose_k(const float* __restrict__ in, float* __restrict__ out,
                                                   unsigned short* __restrict__ out_bf, int R, int Cc)
{
    __shared__ float tl[32][33];
    const int n = blockIdx.z;
    const size_t base = (size_t)n * R * Cc;
    int c0 = blockIdx.x * 32, r0 = blockIdx.y * 32;
    int tx = threadIdx.x & 31, ty0 = threadIdx.x >> 5;
#pragma unroll
    for (int i = 0; i < 32; i += 8)
        tl[ty0 + i][tx] = in[base + (size_t)(r0 + ty0 + i) * Cc + c0 + tx];
    __syncthreads();
#pragma unroll
    for (int i = 0; i < 32; i += 8) {
        float v = tl[tx][ty0 + i];
        size_t o = base + (size_t)(c0 + ty0 + i) * R + r0 + tx;
        out[o] = v;
        out_bf[o] = f2b(v);
    }
}

// ---------------------------------------------------------------- w_asm [tap][ci][co] fp32 -> wT [tap][co][ci] bf16
__global__ __launch_bounds__(256) void cvt_wT_k(const float* __restrict__ w, unsigned short* __restrict__ wT)
{
    __shared__ float tl[32][33];
    const int tap = blockIdx.z;
    const int c0 = blockIdx.x * 32;
    const int o0 = blockIdx.y * 32;
    const int tx = threadIdx.x & 31, ty0 = threadIdx.x >> 5;
#pragma unroll
    for (int i = 0; i < 32; i += 8)
        tl[ty0 + i][tx] = w[((size_t)tap * 256 + c0 + ty0 + i) * 256 + o0 + tx];
    __syncthreads();
#pragma unroll
    for (int i = 0; i < 32; i += 8)
        wT[((size_t)tap * 256 + o0 + ty0 + i) * 256 + c0 + tx] = f2b(tl[tx][ty0 + i]);
}

// ---------------------------------------------------------------- MFMA conv 3x3 (value path, bf16)
__global__ __launch_bounds__(256) void conv_mfma_k(
    const unsigned short* __restrict__ in_bf, const unsigned short* __restrict__ wT,
    const float* __restrict__ bias, unsigned short* __restrict__ ya_bf)
{
    __shared__ short As[128 * 32];
    __shared__ short Bs[128 * 32];
    const int n = blockIdx.z, p0 = blockIdx.x * 128, co0 = blockIdx.y * 128;
    const int tid = threadIdx.x;
    const int w = tid >> 6, wr = w >> 1, wc = w & 1;
    const int lane = tid & 63, lm = lane & 15, lq = lane >> 4;
    const int r = tid >> 1, hf = tid & 1;
    const int p = p0 + r, py = p / WW, px = p % WW;
    const unsigned short* inN = in_bf + (size_t)n * LL * CHN;

    f32x4 acc[4][4];
#pragma unroll
    for (int a = 0; a < 4; a++)
#pragma unroll
        for (int b = 0; b < 4; b++) acc[a][b] = (f32x4){0.f, 0.f, 0.f, 0.f};

    for (int tap = 0; tap < 9; tap++) {
        const int ky = tap / 3, kx = tap - ky * 3;
        const int sy = py + ky - 1, sx = px + kx - 1;
        const bool valid = ((unsigned)sy < HH) && ((unsigned)sx < WW);
        const unsigned short* asrc = inN + (size_t)(sy * WW + sx) * CHN + hf * 16;
        const unsigned short* bsrc = wT + ((size_t)tap * 256 + co0 + r) * 256 + hf * 16;
        for (int ci0 = 0; ci0 < 256; ci0 += 32) {
            u16x8 av0 = (u16x8){0,0,0,0,0,0,0,0}, av1 = (u16x8){0,0,0,0,0,0,0,0};
            if (valid) {
                av0 = *(const u16x8*)(asrc + ci0);
                av1 = *(const u16x8*)(asrc + ci0 + 8);
            }
            u16x8 bv0 = *(const u16x8*)(bsrc + ci0);
            u16x8 bv1 = *(const u16x8*)(bsrc + ci0 + 8);
            __syncthreads();
            *(u16x8*)&As[r * 32 + hf * 16]     = av0;
            *(u16x8*)&As[r * 32 + hf * 16 + 8] = av1;
            *(u16x8*)&Bs[r * 32 + hf * 16]     = bv0;
            *(u16x8*)&Bs[r * 32 + hf * 16 + 8] = bv1;
            __syncthreads();
            bf16x8 af[4], bf[4];
#pragma unroll
            for (int mt = 0; mt < 4; mt++)
                af[mt] = *(const bf16x8*)&As[(wr * 64 + mt * 16 + lm) * 32 + lq * 8];
#pragma unroll
            for (int nt = 0; nt < 4; nt++)
                bf[nt] = *(const bf16x8*)&Bs[(wc * 64 + nt * 16 + lm) * 32 + lq * 8];
#pragma unroll
            for (int mt = 0; mt < 4; mt++)
#pragma unroll
                for (int nt = 0; nt < 4; nt++)
                    acc[mt][nt] = __builtin_amdgcn_mfma_f32_16x16x32_bf16(af[mt], bf[nt], acc[mt][nt], 0, 0, 0);
        }
    }
    float bv[4];
#pragma unroll
    for (int nt = 0; nt < 4; nt++) bv[nt] = bias[co0 + wc * 64 + nt * 16 + lm];
#pragma unroll
    for (int mt = 0; mt < 4; mt++) {
#pragma unroll
        for (int r4 = 0; r4 < 4; r4++) {
            int row = p0 + wr * 64 + mt * 16 + lq * 4 + r4;
            unsigned short* od = ya_bf + ((size_t)n * LL + row) * CHN + co0 + wc * 64;
#pragma unroll
            for (int nt = 0; nt < 4; nt++)
                od[nt * 16 + lm] = f2b(acc[mt][nt][r4] + bv[nt]);
        }
    }
}

// ---------------------------------------------------------------- bf16 transpose: ya_bf (viewed [256][9216]) -> yaT [9216][256]
__global__ __launch_bounds__(256) void transpose_bf_k(const unsigned short* __restrict__ in,
                                                      unsigned short* __restrict__ out)
{
    __shared__ unsigned short tl[64][65];
    const int n = blockIdx.z;
    const size_t base = (size_t)n * LL * CHN;
    const int t0 = blockIdx.x * 64, e0 = blockIdx.y * 64;
    const int tx = threadIdx.x & 63, ty0 = threadIdx.x >> 6;
#pragma unroll
    for (int i = 0; i < 16; i++) {
        int row = ty0 + i * 4;
        tl[row][tx] = in[base + (size_t)(e0 + row) * LL + t0 + tx];
    }
    __syncthreads();
#pragma unroll
    for (int i = 0; i < 16; i++) {
        int row = ty0 + i * 4;
        out[base + (size_t)(t0 + row) * CHN + e0 + tx] = tl[tx][row];
    }
}

// ---------------------------------------------------------------- hashing: codes + squared norms (fp32!)
__global__ __launch_bounds__(256) void hash_k(const float* __restrict__ xmT, const float* __restrict__ rot,
                                              int* __restrict__ codes, float* __restrict__ ssq)
{
    __shared__ float rs[128 * 68];   // [hi][f], stride 68
    for (int e = threadIdx.x; e < 8192; e += 256) {
        int hi = e >> 6, f = e & 63;
        rs[hi * 68 + f] = rot[f * 128 + hi];
    }
    __syncthreads();
    int g = blockIdx.x * 256 + threadIdx.x;
    int n = g / LL, t = g % LL;
    float4 x4[16];
    const float* src = xmT + (size_t)g * CC;
#pragma unroll
    for (int f4 = 0; f4 < 16; f4++) x4[f4] = *(const float4*)(src + f4 * 4);
    float ss = 0.f;
#pragma unroll
    for (int f4 = 0; f4 < 16; f4++)
        ss += x4[f4].x * x4[f4].x + x4[f4].y * x4[f4].y + x4[f4].z * x4[f4].z + x4[f4].w * x4[f4].w;
    ssq[g] = ss;
    for (int h = 0; h < NHASH; h++) {
        float bp = -1e30f, bn = -1e30f;
        int ip = 0, inn = 0;
        for (int i = 0; i < 32; i++) {
            const float* rr = &rs[(h * 32 + i) * 68];
            float d0 = 0.f, d1 = 0.f, d2 = 0.f, d3 = 0.f;
#pragma unroll
            for (int f4 = 0; f4 < 16; f4++) {
                float4 r4 = *(const float4*)(rr + f4 * 4);
                d0 = fmaf(x4[f4].x, r4.x, d0);
                d1 = fmaf(x4[f4].y, r4.y, d1);
                d2 = fmaf(x4[f4].z, r4.z, d2);
                d3 = fmaf(x4[f4].w, r4.w, d3);
            }
            float d = (d0 + d1) + (d2 + d3);
            if (d > bp) { bp = d; ip = i; }
            if (-d > bn) { bn = -d; inn = i; }
        }
        int code = (bp >= bn) ? ip : (32 + inn);
        codes[(size_t)n * NJ + h * LL + t] = code + h * HBK;
    }
}

// ---------------------------------------------------------------- stable counting sort (256 buckets)
__global__ __launch_bounds__(256) void sort_hist_k(const int* __restrict__ codes, int* __restrict__ hist,
                                                   int* __restrict__ rank)
{
    __shared__ int lc[256];
    __shared__ int lh[256];
    const int n = blockIdx.y, seg = blockIdx.x, tid = threadIdx.x;
    int j = seg * 256 + tid;
    int c = codes[(size_t)n * NJ + j];
    lc[tid] = c;
    lh[tid] = 0;
    __syncthreads();
    int r = 0;
    for (int q = 0; q < tid; q++) r += (lc[q] == c) ? 1 : 0;
    atomicAdd(&lh[c], 1);
    __syncthreads();
    rank[(size_t)n * NJ + j] = r;
    hist[(size_t)n * NJ + tid * 144 + seg] = lh[tid];
}

__global__ __launch_bounds__(256) void sort_scan_k(int* __restrict__ hist)
{
    const int n = blockIdx.x;
    const int key = threadIdx.x;
    int* hn = hist + (size_t)n * NJ;
    int sum = 0;
    for (int s = 0; s < 144; s++) sum += hn[key * 144 + s];
    __shared__ int tot[256];
    tot[key] = sum;
    __syncthreads();
    int excl = 0;
    for (int q = 0; q < key; q++) excl += tot[q];
    int run = excl;
    for (int s = 0; s < 144; s++) { int v = hn[key * 144 + s]; hn[key * 144 + s] = run; run += v; }
}

__global__ __launch_bounds__(256) void sort_scatter_k(const int* __restrict__ codes, const int* __restrict__ rank,
                                                      const int* __restrict__ hist, int* __restrict__ sidx,
                                                      int* __restrict__ undo)
{
    const int n = blockIdx.y, seg = blockIdx.x, tid = threadIdx.x;
    int j = seg * 256 + tid;
    int c = codes[(size_t)n * NJ + j];
    int dest = hist[(size_t)n * NJ + c * 144 + seg] + rank[(size_t)n * NJ + j];
    sidx[(size_t)n * NJ + dest] = j;
    undo[(size_t)n * NJ + j] = dest;
}

// ---------------------------------------------------------------- MFMA attention v3
// Separate Qs/Ks/Ps buffers (no overlay) -> P written straight to LDS for all
// chunks, no pbuf across barriers, no scratch spills. waves_per_eu pinned to 4.
#define QSTR 72     // Q/K row stride in shorts
#define PSTR 168    // P row stride in shorts
__global__ __launch_bounds__(1024, 4) __attribute__((amdgpu_waves_per_eu(4, 4))) void attn_mfma_k(
    const unsigned short* __restrict__ xmT_bf, const unsigned short* __restrict__ yaT,
    const float* __restrict__ ssq, const int* __restrict__ sidx,
    unsigned short* __restrict__ Osort, float* __restrict__ bs)
{
    __shared__ short Qs[144 * QSTR];
    __shared__ short Ks[144 * QSTR];
    __shared__ short Ps[144 * PSTR];
    __shared__ int   tIdx[432];
    __shared__ int   voff[432];
    __shared__ float nfs[432];
    __shared__ float qlen[432];
    __shared__ float lsum[144];
    __shared__ float linv[144];

    const int k = blockIdx.x, h = blockIdx.y, n = blockIdx.z;
    const int tid = threadIdx.x;
    const int w = tid >> 6, lane = tid & 63;
    const int lm = lane & 15, lq = lane >> 4;
    const size_t sbase = (size_t)n * NJ + (size_t)h * LL;

    if (tid < 432) {
        int cc = tid / CHK, rr = tid - cc * CHK;
        int c = (cc == 0) ? k : (cc == 1 ? (k + NCHUNK - 1) & (NCHUNK - 1) : (k + 1) & (NCHUNK - 1));
        int j = sidx[sbase + c * CHK + rr];
        int t = j % LL;
        tIdx[tid] = t;
        voff[tid] = t * (CHN * 2);
        float m = fmaxf(ssq[(size_t)n * LL + t], 5e-5f);
        float nf = rsqrtf(m);
        nfs[tid] = nf;
        qlen[tid] = m * nf;   // sqrt(m) = |q| clamped
    }
    __syncthreads();   // tIdx/voff/nfs/qlen ready

    // stage Q rows (raw bf16)
    for (int e = tid; e < 1152; e += 1024) {
        int r = e >> 3, j8 = e & 7;
        u16x8 v = *(const u16x8*)(xmT_bf + ((size_t)n * LL + tIdx[r]) * CC + j8 * 8);
        *(u16x8*)&Qs[r * QSTR + j8 * 8] = v;
    }
    // zero P pad columns 144..159 once; P writes only touch cols 0..143 and Ks never
    // overlays Ps, so the pad stays exactly 0 (NaN-safe under the lsum/PV reads).
    for (int e = tid; e < 2304; e += 1024) {
        int r = e >> 4, c = 144 + (e & 15);
        Ps[r * PSTR + c] = 0;
    }

    const char* vbase = (const char*)(yaT + (size_t)n * LL * CHN + w * 16 + lm);
    f32x4 accO[9];
#pragma unroll
    for (int mt = 0; mt < 9; mt++) accO[mt] = (f32x4){0.f, 0.f, 0.f, 0.f};
    f32x4 accL = (f32x4){0.f, 0.f, 0.f, 0.f};
    bf16x8 onesF, onesL;
#pragma unroll
    for (int i = 0; i < 8; i++) {
        onesF[i] = (short)0x3F80;
        onesL[i] = (lq < 2) ? (short)0x3F80 : (short)0;   // mask pad keys 144..159 (k-step 4, lq>=2)
    }

    for (int cc = 0; cc < 3; cc++) {
        const int c144 = cc * CHK;
        if (cc > 0) {
            // prior Ks readers (cc-1's QK) all completed before cc-1's "Ps ready" barrier
            for (int e = tid; e < 1152; e += 1024) {
                int r = e >> 3, j8 = e & 7;
                u16x8 v = *(const u16x8*)(xmT_bf + ((size_t)n * LL + tIdx[c144 + r]) * CC + j8 * 8);
                *(u16x8*)&Ks[r * QSTR + j8 * 8] = v;
            }
        }
        // V B-frag gathers from global — issued early, consumed after QK (latency hidden)
        bf16x8 vfrag[5];
#pragma unroll
        for (int ks = 0; ks < 5; ks++) {
            int kb = ks * 32 + lq * 8;
            if (kb < 144) {
                int4 o0 = *(const int4*)&voff[c144 + kb];
                int4 o1 = *(const int4*)&voff[c144 + kb + 4];
                vfrag[ks][0] = (short)*(const unsigned short*)(vbase + o0.x);
                vfrag[ks][1] = (short)*(const unsigned short*)(vbase + o0.y);
                vfrag[ks][2] = (short)*(const unsigned short*)(vbase + o0.z);
                vfrag[ks][3] = (short)*(const unsigned short*)(vbase + o0.w);
                vfrag[ks][4] = (short)*(const unsigned short*)(vbase + o1.x);
                vfrag[ks][5] = (short)*(const unsigned short*)(vbase + o1.y);
                vfrag[ks][6] = (short)*(const unsigned short*)(vbase + o1.z);
                vfrag[ks][7] = (short)*(const unsigned short*)(vbase + o1.w);
            } else {
                vfrag[ks] = (bf16x8){0, 0, 0, 0, 0, 0, 0, 0};
            }
        }
        // cc==0: Qs + Ps pad ready; cc>0: Ks ready AND prev chunk's Ps reads drained
        __syncthreads();

        // QK (B^T GEMM) + exp; raw scores post-scaled by key norm; P written straight to LDS
        const short* Bsrc = (cc == 0) ? Qs : Ks;
        for (int tt = w; tt < 81; tt += 16) {
            int mt = tt / 9, nt = tt - mt * 9;
            f32x4 c = {0.f, 0.f, 0.f, 0.f};
#pragma unroll
            for (int ks = 0; ks < 2; ks++) {
                bf16x8 a = *(const bf16x8*)&Qs[(mt * 16 + lm) * QSTR + ks * 32 + lq * 8];
                bf16x8 b = *(const bf16x8*)&Bsrc[(nt * 16 + lm) * QSTR + ks * 32 + lq * 8];
                c = __builtin_amdgcn_mfma_f32_16x16x32_bf16(a, b, c, 0, 0, 0);
            }
            float nfk = nfs[c144 + nt * 16 + lm];
#pragma unroll
            for (int r = 0; r < 4; r++) {
                int mrow = mt * 16 + lq * 4 + r;
                float p = __expf(fmaf(c[r], nfk, -qlen[mrow]));
                Ps[mrow * PSTR + nt * 16 + lm] = (short)f2b(p);
            }
        }
        __syncthreads();   // Ps ready (pad cols are permanent zeros)

        // lsum via ones-MFMA (waves 0..8, mt = w)
        if (w < 9) {
#pragma unroll
            for (int ks = 0; ks < 5; ks++) {
                bf16x8 a = *(const bf16x8*)&Ps[(w * 16 + lm) * PSTR + ks * 32 + lq * 8];
                accL = __builtin_amdgcn_mfma_f32_16x16x32_bf16(a, (ks == 4) ? onesL : onesF, accL, 0, 0, 0);
            }
        }
        // PV: 9 m-tiles, V frags in registers
#pragma unroll
        for (int mt = 0; mt < 9; mt++) {
            f32x4 c = accO[mt];
#pragma unroll
            for (int ks = 0; ks < 5; ks++) {
                bf16x8 a = *(const bf16x8*)&Ps[(mt * 16 + lm) * PSTR + ks * 32 + lq * 8];
                c = __builtin_amdgcn_mfma_f32_16x16x32_bf16(a, vfrag[ks], c, 0, 0, 0);
            }
            accO[mt] = c;
        }
    }

    if (w < 9 && lm == 0) {
#pragma unroll
        for (int r = 0; r < 4; r++) lsum[w * 16 + lq * 4 + r] = accL[r];
    }
    __syncthreads();
    if (tid < 144) {
        float l = lsum[tid];
        linv[tid] = 1.0f / l;
        bs[sbase + tIdx[tid]] = qlen[tid] + __logf(l);
    }
    __syncthreads();

#pragma unroll
    for (int mt = 0; mt < 9; mt++) {
        f32x4 c = accO[mt];
#pragma unroll
        for (int r = 0; r < 4; r++) {
            int mrow = mt * 16 + lq * 4 + r;
            Osort[(sbase + (size_t)k * CHK + mrow) * CHN + w * 16 + lm] = f2b(c[r] * linv[mrow]);
        }
    }
}

// ---------------------------------------------------------------- combine (4 hashes, inline softmax) + transpose + residual
__global__ __launch_bounds__(256) void combfin_k(
    const unsigned short* __restrict__ Osort, const float* __restrict__ bs,
    const int* __restrict__ undo, const float* __restrict__ inp, float* __restrict__ out)
{
    __shared__ float ac[32][260];
    __shared__ int   uS[4][32];
    __shared__ float pS[4][32];
    const int n = blockIdx.y;
    const int t0 = blockIdx.x * 32;
    const int tid = threadIdx.x;
    if (tid < 128) {
        int hh = tid >> 5, tt = tid & 31;
        size_t idx = (size_t)n * NJ + (size_t)hh * LL + t0 + tt;
        uS[hh][tt] = undo[idx];
        pS[hh][tt] = bs[idx];
    }
    __syncthreads();
    if (tid < 32) {
        float b0 = pS[0][tid], b1 = pS[1][tid], b2 = pS[2][tid], b3 = pS[3][tid];
        float mx = fmaxf(fmaxf(b0, b1), fmaxf(b2, b3));
        float e0 = __expf(b0 - mx), e1 = __expf(b1 - mx), e2 = __expf(b2 - mx), e3 = __expf(b3 - mx);
        float inv = 1.f / (e0 + e1 + e2 + e3);
        pS[0][tid] = e0 * inv; pS[1][tid] = e1 * inv; pS[2][tid] = e2 * inv; pS[3][tid] = e3 * inv;
    }
    __syncthreads();
    const int g = tid & 63, tq = tid >> 6;
    for (int tt8 = 0; tt8 < 8; tt8++) {
        int t = tq * 8 + tt8;
        float a0 = 0.f, a1 = 0.f, a2 = 0.f, a3 = 0.f;
#pragma unroll
        for (int hh = 0; hh < 4; hh++) {
            int row = uS[hh][t];
            float p = pS[hh][t];
            ushort4 u = *(const ushort4*)&Osort[((size_t)n * NJ + row) * CHN + g * 4];
            a0 = fmaf(p, b2f(u.x), a0);
            a1 = fmaf(p, b2f(u.y), a1);
            a2 = fmaf(p, b2f(u.z), a2);
            a3 = fmaf(p, b2f(u.w), a3);
        }
        *(float4*)&ac[t][g * 4] = make_float4(a0, a1, a2, a3);
    }
    __syncthreads();
    const int tp = tid & 31, er = tid >> 5;
    const float* inN = inp + (size_t)n * LL * CHN;
    float* outN = out + (size_t)n * LL * CHN;
    for (int it = 0; it < 32; it++) {
        int e = er + it * 8;
        size_t o = (size_t)e * LL + t0 + tp;
        outN[o] = ac[tp][e] * 0.1f + inN[o];
    }
}

// ---------------------------------------------------------------- launch
extern "C" void kernel_launch(void* const* d_in, const int* in_sizes, int n_in,
                              void* d_out, int out_size, void* d_ws, size_t ws_size,
                              hipStream_t stream)
{
    (void)in_sizes; (void)n_in; (void)out_size; (void)ws_size;
    const float* input   = (const float*)d_in[0];
    const float* w_match = (const float*)d_in[1];
    const float* b_match = (const float*)d_in[2];
    const float* w_asm   = (const float*)d_in[3];
    const float* b_asm   = (const float*)d_in[4];
    const float* rot     = (const float*)d_in[5];
    float* out = (float*)d_out;

    char* ws = (char*)d_ws;
    size_t off = 0;
    auto alloc = [&](size_t bytes) -> void* {
        void* p = ws + off;
        off += (bytes + 255) & ~(size_t)255;
        return p;
    };
    unsigned short* in_bf  = (unsigned short*)alloc((size_t)NB * LL * CHN * 2);   // = in_hi
    unsigned short* wT_bf  = (unsigned short*)alloc((size_t)9 * CHN * CHN * 2);
    unsigned short* ya_bf  = (unsigned short*)alloc((size_t)NB * LL * CHN * 2);
    unsigned short* yaT    = (unsigned short*)alloc((size_t)NB * LL * CHN * 2);
    float* xm     = (float*)alloc((size_t)NB * LL * CC * 4);
    float* xmT    = (float*)alloc((size_t)NB * LL * CC * 4);
    unsigned short* xmT_bf = (unsigned short*)alloc((size_t)NB * LL * CC * 2);
    float* ssq    = (float*)alloc((size_t)NB * LL * 4);
    int*   codes  = (int*)  alloc((size_t)NB * NJ * 4);
    int*   rank   = (int*)  alloc((size_t)NB * NJ * 4);
    int*   hist   = (int*)  alloc((size_t)NB * NJ * 4);
    int*   sidx   = (int*)  alloc((size_t)NB * NJ * 4);
    int*   undo   = (int*)  alloc((size_t)NB * NJ * 4);
    float* bs     = (float*)alloc((size_t)NB * NJ * 4);
    unsigned short* Osort = (unsigned short*)alloc((size_t)NB * NJ * CHN * 2);
    unsigned short* wmT_hi = (unsigned short*)alloc((size_t)9 * 64 * CHN * 2);
    unsigned short* wmT_lo = (unsigned short*)alloc((size_t)9 * 64 * CHN * 2);
    // in_lo (18.9 MB) aliases the head of Osort (75.5 MB): in_lo is written by
    // cvt_in_hilo_k and last read by conv_match_mfma_k, both strictly before
    // attn_mfma_k writes Osort on the same stream. Keeps workspace footprint flat.
    unsigned short* in_lo = Osort;

    // input hi/lo split (hi also feeds the value-path conv)
    cvt_in_hilo_k<<<dim3(4608), 256, 0, stream>>>(input, in_bf, in_lo);
    // match path (split-bf16 MFMA — feeds hashing at ~fp32 precision)
    cvt_wm_hilo_k<<<dim3(8, 2, 9), 256, 0, stream>>>(w_match, wmT_hi, wmT_lo);
    conv_match_mfma_k<<<dim3(72, 1, NB), 256, 0, stream>>>(in_bf, in_lo, wmT_hi, wmT_lo, b_match, xm);
    transpose_k<<<dim3(288, 2, NB), 256, 0, stream>>>(xm, xmT, xmT_bf, CC, LL);
    // value path (bf16 MFMA)
    cvt_wT_k<<<dim3(8, 8, 9), 256, 0, stream>>>(w_asm, wT_bf);
    conv_mfma_k<<<dim3(72, 2, NB), 256, 0, stream>>>(in_bf, wT_bf, b_asm, ya_bf);
    transpose_bf_k<<<dim3(144, 4, NB), 256, 0, stream>>>(ya_bf, yaT);
    // hashing + sort
    hash_k<<<dim3(144), 256, 0, stream>>>(xmT, rot, codes, ssq);
    sort_hist_k<<<dim3(144, NB), 256, 0, stream>>>(codes, hist, rank);
    sort_scan_k<<<dim3(NB), 256, 0, stream>>>(hist);
    sort_scatter_k<<<dim3(144, NB), 256, 0, stream>>>(codes, rank, hist, sidx, undo);
    // attention + combine
    attn_mfma_k<<<dim3(NCHUNK, NHASH, NB), 1024, 0, stream>>>(xmT_bf, yaT, ssq, sidx, Osort, bs);
    combfin_k<<<dim3(288, NB), 256, 0, stream>>>(Osort, bs, undo, input, out);
}